// Round 3
// baseline (795.266 us; speedup 1.0000x reference)
//
#include <hip/hip_runtime.h>
#include <hip/hip_bf16.h>
#include <stdint.h>

typedef __attribute__((ext_vector_type(8))) __bf16 bf16x8;
typedef __attribute__((ext_vector_type(4))) float f32x4;

__device__ __forceinline__ float bf2f(unsigned short u) {
  unsigned int x = ((unsigned int)u) << 16;
  float f; __builtin_memcpy(&f, &x, 4); return f;
}
__device__ __forceinline__ unsigned short f2bf(float f) {
  unsigned int x; __builtin_memcpy(&x, &f, 4);
  unsigned int r = x + 0x7fffu + ((x >> 16) & 1u);
  return (unsigned short)(r >> 16);
}
// pack two fp32 -> two bf16 (RNE), low = a, high = b
__device__ __forceinline__ unsigned int pk2(float a, float b) {
  __hip_bfloat162 h = __float22bfloat162_rn(float2{a, b});
  unsigned int u; __builtin_memcpy(&u, &h, 4); return u;
}
// convert 8 consecutive fp32 to 8 bf16 packed in a uint4
__device__ __forceinline__ uint4 cvt8(const float* src) {
  float4 a = *(const float4*)src;
  float4 b = *(const float4*)(src + 4);
  uint4 r;
  r.x = pk2(a.x, a.y); r.y = pk2(a.z, a.w);
  r.z = pk2(b.x, b.y); r.w = pk2(b.z, b.w);
  return r;
}

// ---------------------------------------------------------------------------
// GEMM: C[M,N] = A[M,K] @ W[N,K]^T (+ bias[N]).
// W, bias always fp32 (converted to bf16 at staging). A is fp32 or internal
// bf16 (A_F32). Output fp32 (OUT_F32) or internal bf16. fp32 accumulate.
// 128x128 tile, BK=32, 256 threads = 4 waves (2x2 of 64x64), mfma 16x16x32.
// ---------------------------------------------------------------------------
template <bool A_F32, bool OUT_F32, bool HAS_BIAS>
__global__ __launch_bounds__(256) void gemm_bt(const void* __restrict__ Av,
                                               const float* __restrict__ W,
                                               const float* __restrict__ bias,
                                               void* __restrict__ Cv,
                                               int M, int N, int K) {
  __shared__ __align__(16) unsigned short sA[128 * 32];
  __shared__ __align__(16) unsigned short sB[128 * 32];
  const int tid = threadIdx.x;
  const int lane = tid & 63;
  const int w = tid >> 6;
  const long m0 = (long)blockIdx.y * 128;
  const long n0 = (long)blockIdx.x * 128;
  const int wm = (w >> 1) * 64;
  const int wn = (w & 1) * 64;
  const int fr = lane & 15, fq = lane >> 4;

  const int st_row = tid >> 2;  // 0..63 (piece r adds 64)
  const int st_g = tid & 3;     // 16B(bf16)/8-elem group within 32-elem row

  f32x4 acc[4][4];
#pragma unroll
  for (int i = 0; i < 4; ++i)
#pragma unroll
    for (int j = 0; j < 4; ++j) acc[i][j] = f32x4{0.f, 0.f, 0.f, 0.f};

  const float* Af32 = A_F32 ? (const float*)Av + m0 * K : nullptr;
  const unsigned short* Ab16 = A_F32 ? nullptr : (const unsigned short*)Av + m0 * K;
  const float* Wb = W + n0 * K;

  for (int k0 = 0; k0 < K; k0 += 32) {
    __syncthreads();
#pragma unroll
    for (int r = 0; r < 2; ++r) {
      int row = r * 64 + st_row;
      if (A_F32)
        *(uint4*)&sA[row * 32 + st_g * 8] = cvt8(Af32 + (long)row * K + k0 + st_g * 8);
      else
        *(uint4*)&sA[row * 32 + st_g * 8] =
            *(const uint4*)(Ab16 + (long)row * K + k0 + st_g * 8);
      *(uint4*)&sB[row * 32 + st_g * 8] = cvt8(Wb + (long)row * K + k0 + st_g * 8);
    }
    __syncthreads();
    bf16x8 af[4], bfr[4];
#pragma unroll
    for (int t = 0; t < 4; ++t) {
      af[t]  = *(const bf16x8*)&sA[(wm + t * 16 + fr) * 32 + fq * 8];
      bfr[t] = *(const bf16x8*)&sB[(wn + t * 16 + fr) * 32 + fq * 8];
    }
#pragma unroll
    for (int mt = 0; mt < 4; ++mt)
#pragma unroll
      for (int nt = 0; nt < 4; ++nt)
        acc[mt][nt] = __builtin_amdgcn_mfma_f32_16x16x32_bf16(af[mt], bfr[nt], acc[mt][nt], 0, 0, 0);
  }

#pragma unroll
  for (int nt = 0; nt < 4; ++nt) {
    long n = n0 + wn + nt * 16 + fr;
    float bv = HAS_BIAS ? bias[n] : 0.f;
#pragma unroll
    for (int mt = 0; mt < 4; ++mt)
#pragma unroll
      for (int r = 0; r < 4; ++r) {
        long m = m0 + wm + mt * 16 + fq * 4 + r;
        float v = acc[mt][nt][r] + bv;
        if (OUT_F32)
          ((float*)Cv)[m * N + n] = v;
        else
          ((unsigned short*)Cv)[m * N + n] = f2bf(v);
      }
  }
}

// ---------------------------------------------------------------------------
// RoPE (in-place on bf16 qkv_ws) + fp32 KV cache scatter.
// qkv_ws layout per token (2048): q[12*128] | k[2*128] | v[2*128]
// ---------------------------------------------------------------------------
__global__ __launch_bounds__(256) void rope_scatter(unsigned short* __restrict__ qkv,
                                                    const float* __restrict__ cosb,
                                                    const float* __restrict__ sinb,
                                                    const int* __restrict__ slot_mapping,
                                                    float* __restrict__ kc,
                                                    float* __restrict__ vc) {
  const int m = blockIdx.x;
  const int t = threadIdx.x;
  const int slot = slot_mapping[m];
  const size_t base = (size_t)m * 2048;
  const size_t cbase = (size_t)m * 128;
  for (int p = t; p < 896; p += 256) {
    int head = p >> 6, d = p & 63;
    int off = head < 12 ? head * 128 : 1536 + (head - 12) * 128;
    float x1 = bf2f(qkv[base + off + d]);
    float x2 = bf2f(qkv[base + off + d + 64]);
    float c1 = cosb[cbase + d], s1 = sinb[cbase + d];
    float c2 = cosb[cbase + d + 64], s2 = sinb[cbase + d + 64];
    float o1 = x1 * c1 - x2 * s1;
    float o2 = x2 * c2 + x1 * s2;
    qkv[base + off + d] = f2bf(o1);
    qkv[base + off + d + 64] = f2bf(o2);
    if (head >= 12) {
      int kh = head - 12;
      kc[(size_t)slot * 256 + kh * 128 + d] = o1;
      kc[(size_t)slot * 256 + kh * 128 + d + 64] = o2;
    }
  }
  vc[(size_t)slot * 256 + t] = bf2f(qkv[base + 1792 + t]);
}

// ---------------------------------------------------------------------------
// Flash attention, causal, GQA (12 q-heads over 2 kv-heads). All-bf16 internal.
// Block = (qb, h, b): 64 Q rows, 4 waves x 16 rows; KV tiles of 64.
// ---------------------------------------------------------------------------
__global__ __launch_bounds__(256) void attn_kernel(const unsigned short* __restrict__ qkv,
                                                   unsigned short* __restrict__ out) {
  const int qb = blockIdx.x, h = blockIdx.y, b = blockIdx.z;
  const int kvh = h / 6;
  __shared__ __align__(16) unsigned short sK[64 * 128];
  __shared__ __align__(16) unsigned short sV[128 * 72];
  __shared__ __align__(16) unsigned short sP[4][16 * 72];
  const int tid = threadIdx.x, lane = tid & 63, w = tid >> 6;
  const int fr = lane & 15, fq = lane >> 4;
  const float scale = 0.08838834764831845f;
  const float LOG2E = 1.44269504089f;

  bf16x8 qf[4];
  {
    const unsigned short* qp =
        qkv + ((size_t)(b * 2048 + qb * 64 + w * 16 + fr) * 2048 + h * 128 + fq * 8);
#pragma unroll
    for (int kt = 0; kt < 4; ++kt) qf[kt] = *(const bf16x8*)(qp + kt * 32);
  }
  float m_i[4], l_i[4];
#pragma unroll
  for (int r = 0; r < 4; ++r) { m_i[r] = -3.0e38f; l_i[r] = 0.f; }
  f32x4 accO[8];
#pragma unroll
  for (int i = 0; i < 8; ++i) accO[i] = f32x4{0.f, 0.f, 0.f, 0.f};

  for (int t = 0; t <= qb; ++t) {
    __syncthreads();
    const size_t tok0 = (size_t)(b * 2048 + t * 64);
#pragma unroll
    for (int i = 0; i < 4; ++i) {
      int idx = i * 256 + tid;
      int kv = idx >> 4, g = idx & 15;
      int gp = g ^ (kv & 7);
      *(uint4*)&sK[kv * 128 + gp * 8] =
          *(const uint4*)(qkv + (tok0 + kv) * 2048 + 1536 + kvh * 128 + g * 8);
    }
#pragma unroll
    for (int i = 0; i < 4; ++i) {
      int idx = i * 256 + tid;
      int kv = idx >> 4;
      int d0 = (idx & 15) * 8;
      union { uint4 q; unsigned short u[8]; } cv;
      cv.q = *(const uint4*)(qkv + (tok0 + kv) * 2048 + 1792 + kvh * 128 + d0);
#pragma unroll
      for (int jj = 0; jj < 8; ++jj) {
        int j = (jj + lane) & 7;
        sV[(d0 + j) * 72 + kv] = cv.u[j];
      }
    }
    __syncthreads();

    f32x4 s4[4];
#pragma unroll
    for (int nt = 0; nt < 4; ++nt) s4[nt] = f32x4{0.f, 0.f, 0.f, 0.f};
#pragma unroll
    for (int nt = 0; nt < 4; ++nt) {
      int kvl = nt * 16 + fr;
      int swz = kvl & 7;
#pragma unroll
      for (int kt = 0; kt < 4; ++kt) {
        bf16x8 kf = *(const bf16x8*)&sK[kvl * 128 + ((kt * 4 + fq) ^ swz) * 8];
        s4[nt] = __builtin_amdgcn_mfma_f32_16x16x32_bf16(qf[kt], kf, s4[nt], 0, 0, 0);
      }
    }
    float sc[4][4];
    const bool diag = (t == qb);
#pragma unroll
    for (int nt = 0; nt < 4; ++nt)
#pragma unroll
      for (int r = 0; r < 4; ++r) {
        float v = s4[nt][r] * scale;
        if (diag && (nt * 16 + fr > w * 16 + fq * 4 + r)) v = -1e30f;
        sc[nt][r] = v;
      }
    float pm[4][4];
#pragma unroll
    for (int r = 0; r < 4; ++r) {
      float mx = fmaxf(fmaxf(sc[0][r], sc[1][r]), fmaxf(sc[2][r], sc[3][r]));
#pragma unroll
      for (int off = 1; off < 16; off <<= 1) mx = fmaxf(mx, __shfl_xor(mx, off));
      float mnew = fmaxf(m_i[r], mx);
      float al = exp2f((m_i[r] - mnew) * LOG2E);
      float rs = 0.f;
#pragma unroll
      for (int nt = 0; nt < 4; ++nt) {
        float p = exp2f((sc[nt][r] - mnew) * LOG2E);
        pm[nt][r] = p;
        rs += p;
      }
#pragma unroll
      for (int off = 1; off < 16; off <<= 1) rs += __shfl_xor(rs, off);
      l_i[r] = l_i[r] * al + rs;
      m_i[r] = mnew;
#pragma unroll
      for (int n2 = 0; n2 < 8; ++n2) accO[n2][r] *= al;
    }
#pragma unroll
    for (int nt = 0; nt < 4; ++nt)
#pragma unroll
      for (int r = 0; r < 4; ++r)
        sP[w][(fq * 4 + r) * 72 + nt * 16 + fr] = f2bf(pm[nt][r]);
#pragma unroll
    for (int kt = 0; kt < 2; ++kt) {
      bf16x8 pf = *(const bf16x8*)&sP[w][fr * 72 + kt * 32 + fq * 8];
#pragma unroll
      for (int n2 = 0; n2 < 8; ++n2) {
        bf16x8 vf = *(const bf16x8*)&sV[(n2 * 16 + fr) * 72 + kt * 32 + fq * 8];
        accO[n2] = __builtin_amdgcn_mfma_f32_16x16x32_bf16(pf, vf, accO[n2], 0, 0, 0);
      }
    }
  }

#pragma unroll
  for (int r = 0; r < 4; ++r) {
    float inv = 1.f / l_i[r];
    size_t row = (size_t)(b * 2048 + qb * 64 + w * 16 + fq * 4 + r);
#pragma unroll
    for (int n2 = 0; n2 < 8; ++n2)
      out[row * 1536 + h * 128 + n2 * 16 + fr] = f2bf(accO[n2][r] * inv);
  }
}

// ---------------------------------------------------------------------------
extern "C" void kernel_launch(void* const* d_in, const int* in_sizes, int n_in,
                              void* d_out, int out_size, void* d_ws, size_t ws_size,
                              hipStream_t stream) {
  const float* x    = (const float*)d_in[0];
  const float* cosb = (const float*)d_in[1];
  const float* sinb = (const float*)d_in[2];
  const float* kci  = (const float*)d_in[3];
  const float* vci  = (const float*)d_in[4];
  const int* slot   = (const int*)d_in[5];
  const float* Wqkv = (const float*)d_in[6];
  const float* bqkv = (const float*)d_in[7];
  const float* Wo   = (const float*)d_in[8];

  float* out = (float*)d_out;
  float* kc  = out + (size_t)12582912;   // 4*2048*1536
  float* vc  = kc + (size_t)4194304;     // 16384*2*128

  unsigned short* qkv_ws  = (unsigned short*)d_ws;      // 8192*2048 bf16
  unsigned short* attn_ws = qkv_ws + (size_t)16777216;  // 8192*1536 bf16

  // kv caches: reference scatters into the (zero) input caches
  hipMemcpyAsync(kc, kci, (size_t)4194304 * 4, hipMemcpyDeviceToDevice, stream);
  hipMemcpyAsync(vc, vci, (size_t)4194304 * 4, hipMemcpyDeviceToDevice, stream);

  // 1) qkv = x @ Wqkv^T + b   (fp32 in, bf16 internal out)
  gemm_bt<true, false, true><<<dim3(16, 64), 256, 0, stream>>>(
      x, Wqkv, bqkv, qkv_ws, 8192, 2048, 1536);
  // 2) RoPE q,k in place + scatter k,v into fp32 caches
  rope_scatter<<<dim3(8192), 256, 0, stream>>>(qkv_ws, cosb, sinb, slot, kc, vc);
  // 3) causal GQA flash attention (bf16 internal)
  attn_kernel<<<dim3(32, 12, 4), 256, 0, stream>>>(qkv_ws, attn_ws);
  // 4) out = attn @ Wo^T   (bf16 internal in, fp32 out)
  gemm_bt<false, true, false><<<dim3(12, 64), 256, 0, stream>>>(
      attn_ws, Wo, nullptr, out, 8192, 1536, 1536);
}